// Round 5
// baseline (525.728 us; speedup 1.0000x reference)
//
#include <hip/hip_runtime.h>
#include <hip/hip_bf16.h>

#define BB 4
#define CC 32
#define WW 256
#define HH 256
#define KK 9
#define WH (WW*HH)

// Force a runtime-zero into a VGPR so weight-pointer offsets become
// lane-addressed -> compiler must use global_load (vmcnt), not s_load (lgkmcnt).
// s_load results force lgkmcnt(0) full drains that serialize against ds_read.
__device__ __forceinline__ int zero_vgpr() {
    int z;
    asm volatile("v_mov_b32 %0, 0" : "=v"(z));
    return z;
}

// ---------------- K0: init stats + build weight layouts ---------------------------
// wT1[ic][oc][12] (+pad): k1 weights, 9 taps padded to 12 -> float4 stream
// wdT2[((ch*9+k)*4+cl)*32 + o] (+pad): k3 weights in traversal order
__global__ void k0_init(const float* __restrict__ w_dsc, const float* __restrict__ w_off,
                        float* __restrict__ wT1, float* __restrict__ wdT2,
                        float* __restrict__ stats1, float* __restrict__ stats2) {
    int i = blockIdx.x * 256 + threadIdx.x;
    if (i < 9248) {
        float v = 0.f;
        if (i < 9216) {
            int o = i & 31;
            int t = i >> 5;           // ((ch*9)+k)*4+cl
            int cl = t & 3;
            int t2 = t >> 2;
            int k = t2 % 9;
            int ch = t2 / 9;
            int c = ch * 4 + cl;
            v = w_dsc[(o * 32 + c) * 9 + k];
        }
        wdT2[i] = v;
    }
    if (i < 3856) {
        float v = 0.f;
        if (i < 3840) {
            int j = i % 12;
            int t = i / 12;
            int oc = t % 10;
            int ic = t / 10;
            v = (j < 9) ? w_off[(oc * 32 + ic) * 9 + j] : 0.f;
        }
        wT1[i] = v;
    }
    if (i < 40) stats1[i] = 0.f;
    if (i < 64) stats2[i] = 0.f;
}

// ---------------- K1: 3x3 SAME conv (10 oc), 1 px/thread, VMEM weight stream ------
// Block: (h-half, w-pair, b), 256 threads. LDS: 8ch x 4rows x 132.
__global__ __launch_bounds__(256) void k1_conv(
    const float* __restrict__ x, const float* __restrict__ wT1,
    const float* __restrict__ b_off, float* __restrict__ off_buf,
    float* __restrict__ stats1) {
    __shared__ float tile[8 * 4 * 132];   // 16,896 B

    const int b = blockIdx.z;
    const int w0 = blockIdx.y * 2;
    const int h0 = blockIdx.x * 128;
    const int hl = threadIdx.x & 127;
    const int wi = threadIdx.x >> 7;
    const int w = w0 + wi;
    const int h = h0 + hl;

    float acc[10];
#pragma unroll
    for (int oc = 0; oc < 10; ++oc) acc[oc] = b_off[oc];

    const float* xb = x + (size_t)b * CC * WH;

    const float4* wp = (const float4*)wT1 + zero_vgpr();   // VMEM-forced stream

    for (int ck = 0; ck < 4; ++ck) {
        // stage 8 ch x 4 rows (w0-1..w0+2) x 130 cols (h0-1..h0+128), zero-padded
        for (int t = threadIdx.x; t < 4160; t += 256) {
            int c = t / 520;
            int rem = t - c * 520;
            int r = rem / 130;
            int cl = rem - r * 130;
            int y = w0 - 1 + r;
            int g = h0 - 1 + cl;
            float v = 0.f;
            if (y >= 0 && y < 256 && g >= 0 && g < 256)
                v = xb[(size_t)(ck * 8 + c) * WH + y * 256 + g];
            tile[(c * 4 + r) * 132 + cl] = v;
        }
        __syncthreads();

#pragma unroll
        for (int c = 0; c < 8; ++c) {
            float v[9];
#pragma unroll
            for (int dy = 0; dy < 3; ++dy)
#pragma unroll
                for (int dx = 0; dx < 3; ++dx)
                    v[dy * 3 + dx] = tile[(c * 4 + wi + dy) * 132 + hl + dx];

#pragma unroll
            for (int oc = 0; oc < 10; ++oc) {
                float4 A = wp[0], Bv = wp[1], Cv = wp[2];
                wp += 3;
                float s = fmaf(v[0], A.x, fmaf(v[1], A.y, fmaf(v[2], A.z,
                          fmaf(v[3], A.w, fmaf(v[4], Bv.x, fmaf(v[5], Bv.y,
                          fmaf(v[6], Bv.z, fmaf(v[7], Bv.w, v[8] * Cv.x))))))));
                acc[oc] += s;
            }
        }
        __syncthreads();
    }

#pragma unroll
    for (int oc = 0; oc < 10; ++oc)
        off_buf[((size_t)b * 10 + oc) * WH + (size_t)w * 256 + h] = acc[oc];

    // GN1 stats, block-reduced: group g covers channels {2g,2g+1}
    const int lane = threadIdx.x & 63;
    const int wv = threadIdx.x >> 6;
    __syncthreads();   // done with tile; reuse for reduction
#pragma unroll
    for (int g = 0; g < 5; ++g) {
        float s = acc[2 * g] + acc[2 * g + 1];
        float q = acc[2 * g] * acc[2 * g] + acc[2 * g + 1] * acc[2 * g + 1];
#pragma unroll
        for (int m = 32; m > 0; m >>= 1) {
            s += __shfl_xor(s, m, 64);
            q += __shfl_xor(q, m, 64);
        }
        if (lane == 0) {
            tile[(g * 2 + 0) * 4 + wv] = s;
            tile[(g * 2 + 1) * 4 + wv] = q;
        }
    }
    __syncthreads();
    if (threadIdx.x < 10) {
        int g = threadIdx.x >> 1;
        int which = threadIdx.x & 1;
        float sum = tile[(g * 2 + which) * 4 + 0] + tile[(g * 2 + which) * 4 + 1] +
                    tile[(g * 2 + which) * 4 + 2] + tile[(g * 2 + which) * 4 + 3];
        atomicAdd(&stats1[(b * 5 + g) * 2 + which], sum);
    }
}

// ---------------- K2: finalize GN1 stats -> (mean, istd) --------------------------
__global__ void k2_fin1(const float* __restrict__ stats1, float* __restrict__ s1f) {
    int i = threadIdx.x;
    if (i < 20) {
        const float n = 2.f * WH;
        float s = stats1[2 * i], q = stats1[2 * i + 1];
        float m = s / n;
        float var = q / n - m * m;
        s1f[2 * i] = m;
        s1f[2 * i + 1] = rsqrtf(var + 1e-5f);
    }
}

// ---------------- K3: GN1+tanh+cumsum + LDS bilinear + stride-9 conv --------------
// Block: (b, 4 w-rows, 64 h-cols), 256 threads = 256 px. LDS: 4ch x 14r, PITCH 96.
// Weights streamed via VMEM (vmcnt) so prefetch overlaps ds_read (lgkmcnt).
__global__ __launch_bounds__(256, 4) void k3_sample(
    const float* __restrict__ xin, const float* __restrict__ off_buf,
    const float* __restrict__ s1f, const float* __restrict__ go_scale,
    const float* __restrict__ go_bias, const float* __restrict__ wdT2,
    const float* __restrict__ b_dsc, float* __restrict__ pre_out,
    float* __restrict__ stats2) {
    __shared__ float tile[4 * 14 * 96];   // 21,504 B

    const int b = blockIdx.z;
    const int w0 = blockIdx.y * 4;
    const int h0 = blockIdx.x * 64;
    const int lane = threadIdx.x & 63;
    const int wv = threadIdx.x >> 6;      // wave id = w-row index
    const int h = h0 + lane;
    const int w = w0 + wv;
    const int row0 = w0 - 5;
    const int col0 = h0 - 8;

    // offsets: GN1 + tanh on channels 0..8 -> cumsum
    float t9[9];
    size_t obase = (size_t)b * 10 * WH + (size_t)w * 256 + h;
#pragma unroll
    for (int c = 0; c < 9; ++c) {
        float v = off_buf[obase + (size_t)c * WH];
        int g = c >> 1;
        float mean = s1f[(b * 5 + g) * 2 + 0];
        float istd = s1f[(b * 5 + g) * 2 + 1];
        v = (v - mean) * istd * go_scale[c] + go_bias[c];
        t9[c] = tanhf(v);
    }
    float ycum[9];
    ycum[3] = t9[3];
    ycum[2] = ycum[3] + t9[2];
    ycum[1] = ycum[2] + t9[1];
    ycum[0] = ycum[1] + t9[0];
    ycum[4] = 0.f;
    ycum[5] = t9[5];
    ycum[6] = ycum[5] + t9[6];
    ycum[7] = ycum[6] + t9[7];
    ycum[8] = ycum[7] + t9[8];

    float acc[32];
#pragma unroll
    for (int o = 0; o < 32; ++o) acc[o] = 0.f;

    const float* xb = xin + (size_t)b * CC * WH;
    const float SC = 255.f / 256.f;

    const float4* wp = (const float4*)wdT2 + zero_vgpr();   // VMEM-forced stream

    for (int ch = 0; ch < 8; ++ch) {
        // stage 4 channels x 14 rows x 76 cols (replicate-clamped), float4 loads
        for (int t = threadIdx.x; t < 1064; t += 256) {
            int c = t / 266;              // 14*19
            int rem = t - c * 266;
            int r = rem / 19;
            int cf = rem - r * 19;
            int y = min(max(row0 + r, 0), 255);
            int g0 = col0 + (cf << 2);
            const float* src = xb + (size_t)(ch * 4 + c) * WH + y * 256;
            float4 val;
            if (g0 >= 0 && g0 <= 252) {
                val = *(const float4*)(src + g0);
            } else {
                val.x = src[min(max(g0, 0), 255)];
                val.y = src[min(max(g0 + 1, 0), 255)];
                val.z = src[min(max(g0 + 2, 0), 255)];
                val.w = src[min(max(g0 + 3, 0), 255)];
            }
            *(float4*)(tile + (c * 14 + r) * 96 + (cf << 2)) = val;
        }
        __syncthreads();

#pragma unroll
        for (int k = 0; k < 9; ++k) {
            float py = fminf(fmaxf(((float)w + ycum[k]) * SC, 0.f), 255.f);
            float pxc = fminf(fmaxf((float)(h + k - 4) * SC, 0.f), 255.f);
            float y0f = floorf(py), x0f = floorf(pxc);
            float wy = py - y0f, wx = pxc - x0f;
            int r0 = (int)y0f - row0;
            int r1 = min((int)y0f + 1, 255) - row0;
            int tc = (int)x0f - col0;
            float w00 = (1.f - wy) * (1.f - wx);
            float w01 = (1.f - wy) * wx;
            float w10 = wy * (1.f - wx);
            float w11 = wy * wx;
#pragma unroll
            for (int cl = 0; cl < 4; ++cl) {
                float4 wv4[8];
#pragma unroll
                for (int q = 0; q < 8; ++q) wv4[q] = wp[q];
                wp += 8;

                const float* p0 = tile + (cl * 14 + r0) * 96 + tc;
                const float* p1 = tile + (cl * 14 + r1) * 96 + tc;
                float v = fmaf(w00, p0[0],
                          fmaf(w01, p0[1], fmaf(w10, p1[0], w11 * p1[1])));
#pragma unroll
                for (int q = 0; q < 8; ++q) {
                    acc[q * 4 + 0] = fmaf(v, wv4[q].x, acc[q * 4 + 0]);
                    acc[q * 4 + 1] = fmaf(v, wv4[q].y, acc[q * 4 + 1]);
                    acc[q * 4 + 2] = fmaf(v, wv4[q].z, acc[q * 4 + 2]);
                    acc[q * 4 + 3] = fmaf(v, wv4[q].w, acc[q * 4 + 3]);
                }
            }
        }
        __syncthreads();
    }

    size_t pbase = (size_t)b * CC * WH + (size_t)w * 256 + h;
#pragma unroll
    for (int o = 0; o < 32; ++o) {
        acc[o] += b_dsc[o];
        pre_out[pbase + (size_t)o * WH] = acc[o];
    }

    // GN2 stats, block-reduced: group g covers channels {4g..4g+3}
#pragma unroll
    for (int g = 0; g < 8; ++g) {
        float s = acc[4 * g] + acc[4 * g + 1] + acc[4 * g + 2] + acc[4 * g + 3];
        float q = acc[4 * g] * acc[4 * g] + acc[4 * g + 1] * acc[4 * g + 1] +
                  acc[4 * g + 2] * acc[4 * g + 2] + acc[4 * g + 3] * acc[4 * g + 3];
#pragma unroll
        for (int m = 32; m > 0; m >>= 1) {
            s += __shfl_xor(s, m, 64);
            q += __shfl_xor(q, m, 64);
        }
        if (lane == 0) {
            tile[(g * 2 + 0) * 4 + wv] = s;
            tile[(g * 2 + 1) * 4 + wv] = q;
        }
    }
    __syncthreads();
    if (threadIdx.x < 16) {
        int g = threadIdx.x >> 1;
        int which = threadIdx.x & 1;
        float sum = tile[(g * 2 + which) * 4 + 0] + tile[(g * 2 + which) * 4 + 1] +
                    tile[(g * 2 + which) * 4 + 2] + tile[(g * 2 + which) * 4 + 3];
        atomicAdd(&stats2[(b * 8 + g) * 2 + which], sum);
    }
}

// ---------------- K4: finalize GN2 stats ------------------------------------------
__global__ void k4_fin2(const float* __restrict__ stats2, float* __restrict__ s2f) {
    int i = threadIdx.x;
    if (i < 32) {
        const float n = 4.f * WH;
        float s = stats2[2 * i], q = stats2[2 * i + 1];
        float m = s / n;
        float var = q / n - m * m;
        s2f[2 * i] = m;
        s2f[2 * i + 1] = rsqrtf(var + 1e-5f);
    }
}

// ---------------- K5: GN2 apply + ReLU, float4 (in-place on d_out) ----------------
__global__ __launch_bounds__(256) void k5_gn(float4* __restrict__ out,
                                             const float* __restrict__ s2f,
                                             const float* __restrict__ gs,
                                             const float* __restrict__ gb) {
    int idx = blockIdx.x * 256 + threadIdx.x;   // < 2097152
    int bo = idx >> 14;           // b*32 + o  (16384 float4 per channel-plane)
    int b = bo >> 5;
    int o = bo & 31;
    int g = o >> 2;
    float mean = s2f[(b * 8 + g) * 2 + 0];
    float istd = s2f[(b * 8 + g) * 2 + 1];
    float sc = gs[o] * istd;
    float bi = gb[o] - mean * sc;
    float4 v = out[idx];
    v.x = fmaxf(fmaf(v.x, sc, bi), 0.f);
    v.y = fmaxf(fmaf(v.y, sc, bi), 0.f);
    v.z = fmaxf(fmaf(v.z, sc, bi), 0.f);
    v.w = fmaxf(fmaf(v.w, sc, bi), 0.f);
    out[idx] = v;
}

extern "C" void kernel_launch(void* const* d_in, const int* in_sizes, int n_in,
                              void* d_out, int out_size, void* d_ws, size_t ws_size,
                              hipStream_t stream) {
    const float* x        = (const float*)d_in[0];
    const float* w_off    = (const float*)d_in[1];
    const float* b_off    = (const float*)d_in[2];
    const float* go_scale = (const float*)d_in[3];
    const float* go_bias  = (const float*)d_in[4];
    const float* w_dsc    = (const float*)d_in[5];
    const float* b_dsc    = (const float*)d_in[6];
    const float* gn_scale = (const float*)d_in[7];
    const float* gn_bias  = (const float*)d_in[8];
    float* out = (float*)d_out;

    float* ws      = (float*)d_ws;
    float* off_buf = ws;                              // 2,621,440
    float* wT1     = off_buf + (size_t)BB * 10 * WH;  // 3,856
    float* wdT2    = wT1 + 3856;                      // 9,248
    float* stats1  = wdT2 + 9248;                     // 40
    float* s1f     = stats1 + 40;                     // 40
    float* stats2  = s1f + 40;                        // 64
    float* s2f     = stats2 + 64;                     // 64

    k0_init<<<37, 256, 0, stream>>>(w_dsc, w_off, wT1, wdT2, stats1, stats2);
    k1_conv<<<dim3(2, 128, BB), 256, 0, stream>>>(x, wT1, b_off, off_buf, stats1);
    k2_fin1<<<1, 64, 0, stream>>>(stats1, s1f);
    k3_sample<<<dim3(4, 64, BB), 256, 0, stream>>>(x, off_buf, s1f, go_scale, go_bias,
                                                   wdT2, b_dsc, out, stats2);
    k4_fin2<<<1, 64, 0, stream>>>(stats2, s2f);
    k5_gn<<<8192, 256, 0, stream>>>((float4*)out, s2f, gn_scale, gn_bias);
}

// Round 7
// 307.465 us; speedup vs baseline: 1.7099x; 1.7099x over previous
//
#include <hip/hip_runtime.h>
#include <hip/hip_bf16.h>

#define BB 4
#define CC 32
#define WW 256
#define HH 256
#define KK 9
#define WH (WW*HH)

// ---------------- K0: init stats + build weight layouts ---------------------------
// wT1[ic][oc][12] (+pad): k1 weights, 9 taps padded to 12 -> float4 stream
// wdT2[((ch*9+k)*4+cl)*32 + o] (+pad): k3 weights in traversal order
__global__ void k0_init(const float* __restrict__ w_dsc, const float* __restrict__ w_off,
                        float* __restrict__ wT1, float* __restrict__ wdT2,
                        float* __restrict__ stats1, float* __restrict__ stats2) {
    int i = blockIdx.x * 256 + threadIdx.x;
    if (i < 9248) {
        float v = 0.f;
        if (i < 9216) {
            int o = i & 31;
            int t = i >> 5;           // ((ch*9)+k)*4+cl
            int cl = t & 3;
            int t2 = t >> 2;
            int k = t2 % 9;
            int ch = t2 / 9;
            int c = ch * 4 + cl;
            v = w_dsc[(o * 32 + c) * 9 + k];
        }
        wdT2[i] = v;
    }
    if (i < 3856) {
        float v = 0.f;
        if (i < 3840) {
            int j = i % 12;
            int t = i / 12;
            int oc = t % 10;
            int ic = t / 10;
            v = (j < 9) ? w_off[(oc * 32 + ic) * 9 + j] : 0.f;
        }
        wT1[i] = v;
    }
    if (i < 40) stats1[i] = 0.f;
    if (i < 64) stats2[i] = 0.f;
}

// ---------------- K1: 3x3 SAME conv (10 oc), weights in LDS (broadcast reads) -----
// Block: (h-half, w-pair, b), 256 threads. LDS: tile 16.9 KB + weights 15.4 KB.
__global__ __launch_bounds__(256) void k1_conv(
    const float* __restrict__ x, const float* __restrict__ wT1,
    const float* __restrict__ b_off, float* __restrict__ off_buf,
    float* __restrict__ stats1) {
    __shared__ float tile[8 * 4 * 132];   // 16,896 B
    __shared__ float wlds[3840];          // 15,360 B

    const int b = blockIdx.z;
    const int w0 = blockIdx.y * 2;
    const int h0 = blockIdx.x * 128;
    const int hl = threadIdx.x & 127;
    const int wi = threadIdx.x >> 7;
    const int w = w0 + wi;
    const int h = h0 + hl;

    // stage all k1 weights once (960 float4, coalesced); first barrier covers it
    for (int t = threadIdx.x; t < 960; t += 256)
        ((float4*)wlds)[t] = ((const float4*)wT1)[t];

    float acc[10];
#pragma unroll
    for (int oc = 0; oc < 10; ++oc) acc[oc] = b_off[oc];

    const float* xb = x + (size_t)b * CC * WH;

    for (int ck = 0; ck < 4; ++ck) {
        // stage 8 ch x 4 rows (w0-1..w0+2) x 130 cols (h0-1..h0+128), zero-padded
        for (int t = threadIdx.x; t < 4160; t += 256) {
            int c = t / 520;
            int rem = t - c * 520;
            int r = rem / 130;
            int cl = rem - r * 130;
            int y = w0 - 1 + r;
            int g = h0 - 1 + cl;
            float v = 0.f;
            if (y >= 0 && y < 256 && g >= 0 && g < 256)
                v = xb[(size_t)(ck * 8 + c) * WH + y * 256 + g];
            tile[(c * 4 + r) * 132 + cl] = v;
        }
        __syncthreads();

#pragma unroll
        for (int c = 0; c < 8; ++c) {
            float v[9];
#pragma unroll
            for (int dy = 0; dy < 3; ++dy)
#pragma unroll
                for (int dx = 0; dx < 3; ++dx)
                    v[dy * 3 + dx] = tile[(c * 4 + wi + dy) * 132 + hl + dx];

            const float4* wp = (const float4*)(wlds + (ck * 8 + c) * 120);
#pragma unroll
            for (int oc = 0; oc < 10; ++oc) {
                float4 A = wp[0], Bv = wp[1], Cv = wp[2];
                wp += 3;
                float s = fmaf(v[0], A.x, fmaf(v[1], A.y, fmaf(v[2], A.z,
                          fmaf(v[3], A.w, fmaf(v[4], Bv.x, fmaf(v[5], Bv.y,
                          fmaf(v[6], Bv.z, fmaf(v[7], Bv.w, v[8] * Cv.x))))))));
                acc[oc] += s;
            }
        }
        __syncthreads();
    }

#pragma unroll
    for (int oc = 0; oc < 10; ++oc)
        off_buf[((size_t)b * 10 + oc) * WH + (size_t)w * 256 + h] = acc[oc];

    // GN1 stats, block-reduced: group g covers channels {2g,2g+1}
    const int lane = threadIdx.x & 63;
    const int wv = threadIdx.x >> 6;
    __syncthreads();   // done with tile; reuse for reduction
#pragma unroll
    for (int g = 0; g < 5; ++g) {
        float s = acc[2 * g] + acc[2 * g + 1];
        float q = acc[2 * g] * acc[2 * g] + acc[2 * g + 1] * acc[2 * g + 1];
#pragma unroll
        for (int m = 32; m > 0; m >>= 1) {
            s += __shfl_xor(s, m, 64);
            q += __shfl_xor(q, m, 64);
        }
        if (lane == 0) {
            tile[(g * 2 + 0) * 4 + wv] = s;
            tile[(g * 2 + 1) * 4 + wv] = q;
        }
    }
    __syncthreads();
    if (threadIdx.x < 10) {
        int g = threadIdx.x >> 1;
        int which = threadIdx.x & 1;
        float sum = tile[(g * 2 + which) * 4 + 0] + tile[(g * 2 + which) * 4 + 1] +
                    tile[(g * 2 + which) * 4 + 2] + tile[(g * 2 + which) * 4 + 3];
        atomicAdd(&stats1[(b * 5 + g) * 2 + which], sum);
    }
}

// ---------------- K2: finalize GN1 stats -> (mean, istd) --------------------------
__global__ void k2_fin1(const float* __restrict__ stats1, float* __restrict__ s1f) {
    int i = threadIdx.x;
    if (i < 20) {
        const float n = 2.f * WH;
        float s = stats1[2 * i], q = stats1[2 * i + 1];
        float m = s / n;
        float var = q / n - m * m;
        s1f[2 * i] = m;
        s1f[2 * i + 1] = rsqrtf(var + 1e-5f);
    }
}

// ---------------- K3: GN1+tanh+cumsum + LDS bilinear + stride-9 conv --------------
// Block: (b, 4 w-rows, 64 h-cols), 256 threads = 256 px. LDS tile pitch 96
// (conflict-free) + per-ch weight slice in LDS (uniform ds_read = broadcast,
// fine-grained lgkmcnt -> no s_load full drains).
__global__ __launch_bounds__(256, 4) void k3_sample(
    const float* __restrict__ xin, const float* __restrict__ off_buf,
    const float* __restrict__ s1f, const float* __restrict__ go_scale,
    const float* __restrict__ go_bias, const float* __restrict__ wdT2,
    const float* __restrict__ b_dsc, float* __restrict__ pre_out,
    float* __restrict__ stats2) {
    __shared__ float tile[4 * 14 * 96];   // 21,504 B
    __shared__ float wlds[1152];          // 4,608 B (one ch-slice: 9k x 4cl x 32o)

    const int b = blockIdx.z;
    const int w0 = blockIdx.y * 4;
    const int h0 = blockIdx.x * 64;
    const int lane = threadIdx.x & 63;
    const int wv = threadIdx.x >> 6;      // wave id = w-row index
    const int h = h0 + lane;
    const int w = w0 + wv;
    const int row0 = w0 - 5;
    const int col0 = h0 - 8;

    // offsets: GN1 + tanh on channels 0..8 -> cumsum
    float t9[9];
    size_t obase = (size_t)b * 10 * WH + (size_t)w * 256 + h;
#pragma unroll
    for (int c = 0; c < 9; ++c) {
        float v = off_buf[obase + (size_t)c * WH];
        int g = c >> 1;
        float mean = s1f[(b * 5 + g) * 2 + 0];
        float istd = s1f[(b * 5 + g) * 2 + 1];
        v = (v - mean) * istd * go_scale[c] + go_bias[c];
        t9[c] = tanhf(v);
    }
    float ycum[9];
    ycum[3] = t9[3];
    ycum[2] = ycum[3] + t9[2];
    ycum[1] = ycum[2] + t9[1];
    ycum[0] = ycum[1] + t9[0];
    ycum[4] = 0.f;
    ycum[5] = t9[5];
    ycum[6] = ycum[5] + t9[6];
    ycum[7] = ycum[6] + t9[7];
    ycum[8] = ycum[7] + t9[8];

    float acc[32];
#pragma unroll
    for (int o = 0; o < 32; ++o) acc[o] = 0.f;

    const float* xb = xin + (size_t)b * CC * WH;
    const float SC = 255.f / 256.f;

    for (int ch = 0; ch < 8; ++ch) {
        // stage 4 channels x 14 rows x 76 cols (replicate-clamped), float4 loads
        for (int t = threadIdx.x; t < 1064; t += 256) {
            int c = t / 266;              // 14*19
            int rem = t - c * 266;
            int r = rem / 19;
            int cf = rem - r * 19;
            int y = min(max(row0 + r, 0), 255);
            int g0 = col0 + (cf << 2);
            const float* src = xb + (size_t)(ch * 4 + c) * WH + y * 256;
            float4 val;
            if (g0 >= 0 && g0 <= 252) {
                val = *(const float4*)(src + g0);
            } else {
                val.x = src[min(max(g0, 0), 255)];
                val.y = src[min(max(g0 + 1, 0), 255)];
                val.z = src[min(max(g0 + 2, 0), 255)];
                val.w = src[min(max(g0 + 3, 0), 255)];
            }
            *(float4*)(tile + (c * 14 + r) * 96 + (cf << 2)) = val;
        }
        // stage this ch's weight slice (288 float4, coalesced) — strided: 288 > 256!
        for (int t = threadIdx.x; t < 288; t += 256)
            ((float4*)wlds)[t] = ((const float4*)(wdT2 + ch * 1152))[t];
        __syncthreads();

#pragma unroll
        for (int k = 0; k < 9; ++k) {
            float py = fminf(fmaxf(((float)w + ycum[k]) * SC, 0.f), 255.f);
            float pxc = fminf(fmaxf((float)(h + k - 4) * SC, 0.f), 255.f);
            float y0f = floorf(py), x0f = floorf(pxc);
            float wy = py - y0f, wx = pxc - x0f;
            int r0 = (int)y0f - row0;
            int r1 = min((int)y0f + 1, 255) - row0;
            int tc = (int)x0f - col0;
            float w00 = (1.f - wy) * (1.f - wx);
            float w01 = (1.f - wy) * wx;
            float w10 = wy * (1.f - wx);
            float w11 = wy * wx;
#pragma unroll
            for (int cl = 0; cl < 4; ++cl) {
                const float4* wp = (const float4*)(wlds + (k * 4 + cl) * 32);
                const float* p0 = tile + (cl * 14 + r0) * 96 + tc;
                const float* p1 = tile + (cl * 14 + r1) * 96 + tc;
                float v = fmaf(w00, p0[0],
                          fmaf(w01, p0[1], fmaf(w10, p1[0], w11 * p1[1])));
#pragma unroll
                for (int q = 0; q < 8; ++q) {
                    float4 wv4 = wp[q];
                    acc[q * 4 + 0] = fmaf(v, wv4.x, acc[q * 4 + 0]);
                    acc[q * 4 + 1] = fmaf(v, wv4.y, acc[q * 4 + 1]);
                    acc[q * 4 + 2] = fmaf(v, wv4.z, acc[q * 4 + 2]);
                    acc[q * 4 + 3] = fmaf(v, wv4.w, acc[q * 4 + 3]);
                }
            }
        }
        __syncthreads();
    }

    size_t pbase = (size_t)b * CC * WH + (size_t)w * 256 + h;
#pragma unroll
    for (int o = 0; o < 32; ++o) {
        acc[o] += b_dsc[o];
        pre_out[pbase + (size_t)o * WH] = acc[o];
    }

    // GN2 stats, block-reduced: group g covers channels {4g..4g+3}
#pragma unroll
    for (int g = 0; g < 8; ++g) {
        float s = acc[4 * g] + acc[4 * g + 1] + acc[4 * g + 2] + acc[4 * g + 3];
        float q = acc[4 * g] * acc[4 * g] + acc[4 * g + 1] * acc[4 * g + 1] +
                  acc[4 * g + 2] * acc[4 * g + 2] + acc[4 * g + 3] * acc[4 * g + 3];
#pragma unroll
        for (int m = 32; m > 0; m >>= 1) {
            s += __shfl_xor(s, m, 64);
            q += __shfl_xor(q, m, 64);
        }
        if (lane == 0) {
            tile[(g * 2 + 0) * 4 + wv] = s;
            tile[(g * 2 + 1) * 4 + wv] = q;
        }
    }
    __syncthreads();
    if (threadIdx.x < 16) {
        int g = threadIdx.x >> 1;
        int which = threadIdx.x & 1;
        float sum = tile[(g * 2 + which) * 4 + 0] + tile[(g * 2 + which) * 4 + 1] +
                    tile[(g * 2 + which) * 4 + 2] + tile[(g * 2 + which) * 4 + 3];
        atomicAdd(&stats2[(b * 8 + g) * 2 + which], sum);
    }
}

// ---------------- K4: finalize GN2 stats ------------------------------------------
__global__ void k4_fin2(const float* __restrict__ stats2, float* __restrict__ s2f) {
    int i = threadIdx.x;
    if (i < 32) {
        const float n = 4.f * WH;
        float s = stats2[2 * i], q = stats2[2 * i + 1];
        float m = s / n;
        float var = q / n - m * m;
        s2f[2 * i] = m;
        s2f[2 * i + 1] = rsqrtf(var + 1e-5f);
    }
}

// ---------------- K5: GN2 apply + ReLU, float4 (in-place on d_out) ----------------
__global__ __launch_bounds__(256) void k5_gn(float4* __restrict__ out,
                                             const float* __restrict__ s2f,
                                             const float* __restrict__ gs,
                                             const float* __restrict__ gb) {
    int idx = blockIdx.x * 256 + threadIdx.x;   // < 2097152
    int bo = idx >> 14;           // b*32 + o  (16384 float4 per channel-plane)
    int b = bo >> 5;
    int o = bo & 31;
    int g = o >> 2;
    float mean = s2f[(b * 8 + g) * 2 + 0];
    float istd = s2f[(b * 8 + g) * 2 + 1];
    float sc = gs[o] * istd;
    float bi = gb[o] - mean * sc;
    float4 v = out[idx];
    v.x = fmaxf(fmaf(v.x, sc, bi), 0.f);
    v.y = fmaxf(fmaf(v.y, sc, bi), 0.f);
    v.z = fmaxf(fmaf(v.z, sc, bi), 0.f);
    v.w = fmaxf(fmaf(v.w, sc, bi), 0.f);
    out[idx] = v;
}

extern "C" void kernel_launch(void* const* d_in, const int* in_sizes, int n_in,
                              void* d_out, int out_size, void* d_ws, size_t ws_size,
                              hipStream_t stream) {
    const float* x        = (const float*)d_in[0];
    const float* w_off    = (const float*)d_in[1];
    const float* b_off    = (const float*)d_in[2];
    const float* go_scale = (const float*)d_in[3];
    const float* go_bias  = (const float*)d_in[4];
    const float* w_dsc    = (const float*)d_in[5];
    const float* b_dsc    = (const float*)d_in[6];
    const float* gn_scale = (const float*)d_in[7];
    const float* gn_bias  = (const float*)d_in[8];
    float* out = (float*)d_out;

    float* ws      = (float*)d_ws;
    float* off_buf = ws;                              // 2,621,440
    float* wT1     = off_buf + (size_t)BB * 10 * WH;  // 3,856
    float* wdT2    = wT1 + 3856;                      // 9,248
    float* stats1  = wdT2 + 9248;                     // 40
    float* s1f     = stats1 + 40;                     // 40
    float* stats2  = s1f + 40;                        // 64
    float* s2f     = stats2 + 64;                     // 64

    k0_init<<<37, 256, 0, stream>>>(w_dsc, w_off, wT1, wdT2, stats1, stats2);
    k1_conv<<<dim3(2, 128, BB), 256, 0, stream>>>(x, wT1, b_off, off_buf, stats1);
    k2_fin1<<<1, 64, 0, stream>>>(stats1, s1f);
    k3_sample<<<dim3(4, 64, BB), 256, 0, stream>>>(x, off_buf, s1f, go_scale, go_bias,
                                                   wdT2, b_dsc, out, stats2);
    k4_fin2<<<1, 64, 0, stream>>>(stats2, s2f);
    k5_gn<<<8192, 256, 0, stream>>>((float4*)out, s2f, gn_scale, gn_bias);
}

// Round 8
// 249.038 us; speedup vs baseline: 2.1110x; 1.2346x over previous
//
#include <hip/hip_runtime.h>
#include <hip/hip_bf16.h>

#define BB 4
#define CC 32
#define WW 256
#define HH 256
#define WH (WW*HH)

typedef __attribute__((ext_vector_type(8))) short bf16x8;
typedef __attribute__((ext_vector_type(4))) short bf16x4;
typedef __attribute__((ext_vector_type(4))) float f32x4;

__device__ __forceinline__ short f2bf(float x) {   // RNE fp32->bf16
    union { float f; unsigned u; } a; a.f = x;
    unsigned r = (a.u + 0x7FFF + ((a.u >> 16) & 1)) >> 16;
    return (short)r;
}

// ---------------- K0: build B-fragment tables (bf16, frag-linear) + zero stats ----
// Frag map (assumed, same for A and B): element j of lane l covers k = (l>>4)*8+j,
// k = tap*4+cl within a 4-channel chunk (taps 0..7); tap8 block: k = channel.
__global__ void k0_init(const float* __restrict__ w_dsc, const float* __restrict__ w_off,
                        unsigned short* __restrict__ B3f, unsigned short* __restrict__ B8f,
                        unsigned short* __restrict__ B1f, unsigned short* __restrict__ B18f,
                        float* __restrict__ stats1, float* __restrict__ stats2) {
    int i = blockIdx.x * 256 + threadIdx.x;
    if (i < 8192) {                       // k3 main: [ch][nt][lane][j]
        int j = i & 7, l = (i >> 3) & 63, nt = (i >> 9) & 1, ch = i >> 10;
        int o = nt * 16 + (l & 15);
        int kl = ((l >> 4) << 3) | j;
        int tap = kl >> 2, cl = kl & 3;
        B3f[i] = (unsigned short)f2bf(w_dsc[(o * 32 + ch * 4 + cl) * 9 + tap]);
    } else if (i < 9216) {                // k3 tap8: [nt][lane][j], k8 = channel
        int e = i - 8192;
        int j = e & 7, l = (e >> 3) & 63, nt = e >> 9;
        int o = nt * 16 + (l & 15);
        int k8 = ((l >> 4) << 3) | j;
        B8f[e] = (unsigned short)f2bf(w_dsc[(o * 32 + k8) * 9 + 8]);
    } else if (i < 13312) {               // k1 main: [ch][lane][j], N=16 (10 real)
        int e = i - 9216;
        int j = e & 7, l = (e >> 3) & 63, ch = e >> 9;
        int o = l & 15;
        int kl = ((l >> 4) << 3) | j;
        int tap = kl >> 2, cl = kl & 3;
        B1f[e] = (o < 10) ? (unsigned short)f2bf(w_off[(o * 32 + ch * 4 + cl) * 9 + tap]) : 0;
    } else if (i < 13824) {               // k1 tap8
        int e = i - 13312;
        int j = e & 7, l = (e >> 3) & 63;
        int o = l & 15;
        int k8 = ((l >> 4) << 3) | j;
        B18f[e] = (o < 10) ? (unsigned short)f2bf(w_off[(o * 32 + k8) * 9 + 8]) : 0;
    }
    if (i < 40) stats1[i] = 0.f;
    if (i < 64) stats2[i] = 0.f;
}

// ---------------- K1: 3x3 SAME conv (10 oc) as implicit MFMA GEMM ----------------
// Block: (h-half, w-pair, b), 256 thr = 256 px (2w x 128h). M=256, N=16, K=288.
__global__ __launch_bounds__(256, 3) void k1_conv(
    const float* __restrict__ x, const unsigned short* __restrict__ B1f,
    const unsigned short* __restrict__ B18f, const float* __restrict__ b_off,
    float* __restrict__ off_buf, float* __restrict__ stats1) {
    __shared__ float tile[4 * 4 * 132];     // 8,448 B
    __shared__ short Apan[16 * 64 * 8];     // 16 KB, frag-linear per M-tile
    __shared__ short A8pan[16 * 64 * 8];    // 16 KB, tap8 K=32 panel

    const int b = blockIdx.z;
    const int w0 = blockIdx.y * 2;
    const int h0 = blockIdx.x * 128;
    const int p = threadIdx.x;
    const int lane = p & 63;
    const int wv = p >> 6;
    const int hl = p & 127;
    const int wi = p >> 7;
    const int mt = p >> 4;
    const int mrow = p & 15;

    bf16x8 Bf[8], B8g;
    {
        const bf16x8* bp = (const bf16x8*)B1f;
#pragma unroll
        for (int ch = 0; ch < 8; ++ch) Bf[ch] = bp[ch * 64 + lane];
        B8g = ((const bf16x8*)B18f)[lane];
    }

    f32x4 acc[4];
#pragma unroll
    for (int i = 0; i < 4; ++i) acc[i] = (f32x4){0.f, 0.f, 0.f, 0.f};

    const float* xb = x + (size_t)b * CC * WH;

#pragma unroll
    for (int ch = 0; ch < 8; ++ch) {
        for (int t = threadIdx.x; t < 2080; t += 256) {  // 4ch x 4rows x 130cols
            int c = t / 520;
            int rem = t - c * 520;
            int r = rem / 130;
            int cl = rem - r * 130;
            int y = w0 - 1 + r;
            int g = h0 - 1 + cl;
            float v = 0.f;
            if (y >= 0 && y < 256 && g >= 0 && g < 256)
                v = xb[(size_t)(ch * 4 + c) * WH + y * 256 + g];
            tile[(c * 4 + r) * 132 + cl] = v;
        }
        __syncthreads();   // tile ready; also drains prev iter's A-frag reads

#pragma unroll
        for (int kg = 0; kg < 4; ++kg) {
            bf16x8 pv;
#pragma unroll
            for (int t = 0; t < 2; ++t) {
                int tap = kg * 2 + t;
                int dy = tap / 3, dx = tap - dy * 3;
#pragma unroll
                for (int cl = 0; cl < 4; ++cl)
                    pv[t * 4 + cl] = f2bf(tile[(cl * 4 + wi + dy) * 132 + hl + dx]);
            }
            *(bf16x8*)&Apan[mt * 512 + (kg * 16 + mrow) * 8] = pv;
        }
        {
            bf16x4 pv8;
#pragma unroll
            for (int cl = 0; cl < 4; ++cl)
                pv8[cl] = f2bf(tile[(cl * 4 + wi + 2) * 132 + hl + 2]);
            *(bf16x4*)&A8pan[mt * 512 + ((ch >> 1) * 16 + mrow) * 8 + (ch & 1) * 4] = pv8;
        }
        __syncthreads();   // A-panel ready

#pragma unroll
        for (int i = 0; i < 4; ++i) {
            bf16x8 a = *(const bf16x8*)&Apan[((wv * 4 + i) * 64 + lane) * 8];
            acc[i] = __builtin_amdgcn_mfma_f32_16x16x32_bf16(a, Bf[ch], acc[i], 0, 0, 0);
        }
    }
#pragma unroll
    for (int i = 0; i < 4; ++i) {          // tap8 K=32 block
        bf16x8 a = *(const bf16x8*)&A8pan[((wv * 4 + i) * 64 + lane) * 8];
        acc[i] = __builtin_amdgcn_mfma_f32_16x16x32_bf16(a, B8g, acc[i], 0, 0, 0);
    }

    const int oc = lane & 15;
    float bias = (oc < 10) ? b_off[oc] : 0.f;
#pragma unroll
    for (int i = 0; i < 4; ++i)
#pragma unroll
        for (int r = 0; r < 4; ++r) acc[i][r] += bias;

    if (oc < 10) {
#pragma unroll
        for (int i = 0; i < 4; ++i) {
            int px = (wv * 4 + i) * 16 + (lane >> 4) * 4;
            size_t addr = (size_t)(b * 10 + oc) * WH +
                          (size_t)(w0 + (px >> 7)) * 256 + h0 + (px & 127);
            *(f32x4*)&off_buf[addr] = acc[i];
        }
    }

    // GN1 stats from C-frags (cols = oc; oc>=10 are exact zeros)
    float s = 0.f, q = 0.f;
#pragma unroll
    for (int i = 0; i < 4; ++i)
#pragma unroll
        for (int r = 0; r < 4; ++r) { float v = acc[i][r]; s += v; q += v * v; }
    s += __shfl_xor(s, 1, 64);  q += __shfl_xor(q, 1, 64);
    s += __shfl_xor(s, 16, 64); q += __shfl_xor(q, 16, 64);
    s += __shfl_xor(s, 32, 64); q += __shfl_xor(q, 32, 64);
    __syncthreads();
    float* scratch = tile;
    if (lane < 10 && !(lane & 1)) {
        int g = lane >> 1;
        scratch[(g * 2 + 0) * 4 + wv] = s;
        scratch[(g * 2 + 1) * 4 + wv] = q;
    }
    __syncthreads();
    if (threadIdx.x < 10) {
        int g = threadIdx.x >> 1, which = threadIdx.x & 1;
        float sum = scratch[(g * 2 + which) * 4 + 0] + scratch[(g * 2 + which) * 4 + 1] +
                    scratch[(g * 2 + which) * 4 + 2] + scratch[(g * 2 + which) * 4 + 3];
        atomicAdd(&stats1[(b * 5 + g) * 2 + which], sum);
    }
}

// ---------------- K2: finalize GN1 stats ------------------------------------------
__global__ void k2_fin1(const float* __restrict__ stats1, float* __restrict__ s1f) {
    int i = threadIdx.x;
    if (i < 20) {
        const float n = 2.f * WH;
        float s = stats1[2 * i], q = stats1[2 * i + 1];
        float m = s / n;
        float var = q / n - m * m;
        s1f[2 * i] = m;
        s1f[2 * i + 1] = rsqrtf(var + 1e-5f);
    }
}

// ---------------- K3: bilinear sampling as implicit MFMA GEMM ---------------------
// Block: (b, 4 w-rows, 64 h-cols), 256 thr = 256 px. M=256, N=32, K=288.
__global__ __launch_bounds__(256, 2) void k3_sample(
    const float* __restrict__ xin, const float* __restrict__ off_buf,
    const float* __restrict__ s1f, const float* __restrict__ go_scale,
    const float* __restrict__ go_bias, const unsigned short* __restrict__ B3f,
    const unsigned short* __restrict__ B8f, const float* __restrict__ b_dsc,
    float* __restrict__ pre_out, float* __restrict__ stats2) {
    __shared__ float tile[4 * 14 * 96];     // 21.5 KB, pitch 96 (mod 32 == 0)
    __shared__ short Apan[16 * 64 * 8];     // 16 KB
    __shared__ short A8pan[16 * 64 * 8];    // 16 KB

    const int b = blockIdx.z;
    const int w0 = blockIdx.y * 4;
    const int h0 = blockIdx.x * 64;
    const int p = threadIdx.x;
    const int lane = p & 63;
    const int wv = p >> 6;
    const int h = h0 + (p & 63);
    const int w = w0 + (p >> 6);
    const int mt = p >> 4;
    const int mrow = p & 15;
    const int row0 = w0 - 5;
    const int col0 = h0 - 8;

    bf16x8 Bf[8][2], B8g[2];
    {
        const bf16x8* bp = (const bf16x8*)B3f;
#pragma unroll
        for (int ch = 0; ch < 8; ++ch) {
            Bf[ch][0] = bp[(ch * 2 + 0) * 64 + lane];
            Bf[ch][1] = bp[(ch * 2 + 1) * 64 + lane];
        }
        B8g[0] = ((const bf16x8*)B8f)[lane];
        B8g[1] = ((const bf16x8*)B8f)[64 + lane];
    }

    // offsets: GN1 + tanh + cumsum (per own pixel)
    float t9[9];
    size_t obase = (size_t)b * 10 * WH + (size_t)w * 256 + h;
#pragma unroll
    for (int c = 0; c < 9; ++c) {
        float v = off_buf[obase + (size_t)c * WH];
        int g = c >> 1;
        float mean = s1f[(b * 5 + g) * 2 + 0];
        float istd = s1f[(b * 5 + g) * 2 + 1];
        v = (v - mean) * istd * go_scale[c] + go_bias[c];
        t9[c] = tanhf(v);
    }
    float ycum[9];
    ycum[3] = t9[3];
    ycum[2] = ycum[3] + t9[2];
    ycum[1] = ycum[2] + t9[1];
    ycum[0] = ycum[1] + t9[0];
    ycum[4] = 0.f;
    ycum[5] = t9[5];
    ycum[6] = ycum[5] + t9[6];
    ycum[7] = ycum[6] + t9[7];
    ycum[8] = ycum[7] + t9[8];

    f32x4 acc[4][2];
#pragma unroll
    for (int i = 0; i < 4; ++i) {
        acc[i][0] = (f32x4){0.f, 0.f, 0.f, 0.f};
        acc[i][1] = (f32x4){0.f, 0.f, 0.f, 0.f};
    }

    const float* xb = xin + (size_t)b * CC * WH;
    const float SC = 255.f / 256.f;

#pragma unroll
    for (int ch = 0; ch < 8; ++ch) {
        for (int t = threadIdx.x; t < 1064; t += 256) {  // 4ch x 14r x 76c
            int c = t / 266;
            int rem = t - c * 266;
            int r = rem / 19;
            int cf = rem - r * 19;
            int y = min(max(row0 + r, 0), 255);
            int g0 = col0 + (cf << 2);
            const float* src = xb + (size_t)(ch * 4 + c) * WH + y * 256;
            float4 val;
            if (g0 >= 0 && g0 <= 252) {
                val = *(const float4*)(src + g0);
            } else {
                val.x = src[min(max(g0, 0), 255)];
                val.y = src[min(max(g0 + 1, 0), 255)];
                val.z = src[min(max(g0 + 2, 0), 255)];
                val.w = src[min(max(g0 + 3, 0), 255)];
            }
            *(float4*)(tile + (c * 14 + r) * 96 + (cf << 2)) = val;
        }
        __syncthreads();   // tile ready; drains prev iter's A-frag reads

#pragma unroll
        for (int kg = 0; kg < 4; ++kg) {
            bf16x8 pv;
#pragma unroll
            for (int t = 0; t < 2; ++t) {
                int k = kg * 2 + t;
                float py = fminf(fmaxf(((float)w + ycum[k]) * SC, 0.f), 255.f);
                float pxc = fminf(fmaxf((float)(h + k - 4) * SC, 0.f), 255.f);
                float y0f = floorf(py), x0f = floorf(pxc);
                float wy = py - y0f, wx = pxc - x0f;
                int r0 = (int)y0f - row0;
                int r1 = min((int)y0f + 1, 255) - row0;
                int tc = (int)x0f - col0;
                float w00 = (1.f - wy) * (1.f - wx);
                float w01 = (1.f - wy) * wx;
                float w10 = wy * (1.f - wx);
                float w11 = wy * wx;
#pragma unroll
                for (int cl = 0; cl < 4; ++cl) {
                    const float* p0 = tile + (cl * 14 + r0) * 96 + tc;
                    const float* p1 = tile + (cl * 14 + r1) * 96 + tc;
                    float v = fmaf(w00, p0[0],
                              fmaf(w01, p0[1], fmaf(w10, p1[0], w11 * p1[1])));
                    pv[t * 4 + cl] = f2bf(v);
                }
            }
            *(bf16x8*)&Apan[mt * 512 + (kg * 16 + mrow) * 8] = pv;
        }
        {   // tap k=8
            float py = fminf(fmaxf(((float)w + ycum[8]) * SC, 0.f), 255.f);
            float pxc = fminf(fmaxf((float)(h + 4) * SC, 0.f), 255.f);
            float y0f = floorf(py), x0f = floorf(pxc);
            float wy = py - y0f, wx = pxc - x0f;
            int r0 = (int)y0f - row0;
            int r1 = min((int)y0f + 1, 255) - row0;
            int tc = (int)x0f - col0;
            float w00 = (1.f - wy) * (1.f - wx);
            float w01 = (1.f - wy) * wx;
            float w10 = wy * (1.f - wx);
            float w11 = wy * wx;
            bf16x4 pv8;
#pragma unroll
            for (int cl = 0; cl < 4; ++cl) {
                const float* p0 = tile + (cl * 14 + r0) * 96 + tc;
                const float* p1 = tile + (cl * 14 + r1) * 96 + tc;
                float v = fmaf(w00, p0[0],
                          fmaf(w01, p0[1], fmaf(w10, p1[0], w11 * p1[1])));
                pv8[cl] = f2bf(v);
            }
            *(bf16x4*)&A8pan[mt * 512 + ((ch >> 1) * 16 + mrow) * 8 + (ch & 1) * 4] = pv8;
        }
        __syncthreads();   // A-panel ready

#pragma unroll
        for (int i = 0; i < 4; ++i) {
            bf16x8 a = *(const bf16x8*)&Apan[((wv * 4 + i) * 64 + lane) * 8];
            acc[i][0] = __builtin_amdgcn_mfma_f32_16x16x32_bf16(a, Bf[ch][0], acc[i][0], 0, 0, 0);
            acc[i][1] = __builtin_amdgcn_mfma_f32_16x16x32_bf16(a, Bf[ch][1], acc[i][1], 0, 0, 0);
        }
    }
#pragma unroll
    for (int i = 0; i < 4; ++i) {          // tap8 K=32 block
        bf16x8 a = *(const bf16x8*)&A8pan[((wv * 4 + i) * 64 + lane) * 8];
        acc[i][0] = __builtin_amdgcn_mfma_f32_16x16x32_bf16(a, B8g[0], acc[i][0], 0, 0, 0);
        acc[i][1] = __builtin_amdgcn_mfma_f32_16x16x32_bf16(a, B8g[1], acc[i][1], 0, 0, 0);
    }

    const int oc0 = lane & 15;
    float bias0 = b_dsc[oc0];
    float bias1 = b_dsc[16 + oc0];
#pragma unroll
    for (int i = 0; i < 4; ++i)
#pragma unroll
        for (int r = 0; r < 4; ++r) { acc[i][0][r] += bias0; acc[i][1][r] += bias1; }

#pragma unroll
    for (int i = 0; i < 4; ++i) {
        int px = (wv * 4 + i) * 16 + (lane >> 4) * 4;
        size_t rowoff = (size_t)(w0 + (px >> 6)) * 256 + h0 + (px & 63);
        *(f32x4*)&pre_out[(size_t)(b * 32 + oc0) * WH + rowoff] = acc[i][0];
        *(f32x4*)&pre_out[(size_t)(b * 32 + 16 + oc0) * WH + rowoff] = acc[i][1];
    }

    // GN2 stats from C-frags: group = oc>>2 (4-col quads)
    float s0 = 0.f, q0 = 0.f, s1 = 0.f, q1 = 0.f;
#pragma unroll
    for (int i = 0; i < 4; ++i)
#pragma unroll
        for (int r = 0; r < 4; ++r) {
            float v0 = acc[i][0][r], v1 = acc[i][1][r];
            s0 += v0; q0 += v0 * v0; s1 += v1; q1 += v1 * v1;
        }
#pragma unroll
    for (int m = 0; m < 4; ++m) {
        int d = (m == 0) ? 1 : (m == 1) ? 2 : (m == 2) ? 16 : 32;
        s0 += __shfl_xor(s0, d, 64); q0 += __shfl_xor(q0, d, 64);
        s1 += __shfl_xor(s1, d, 64); q1 += __shfl_xor(q1, d, 64);
    }
    __syncthreads();
    float* scratch = tile;
    if (lane < 16 && !(lane & 3)) {
        int g = lane >> 2;
        scratch[((0 * 4 + g) * 2 + 0) * 4 + wv] = s0;
        scratch[((0 * 4 + g) * 2 + 1) * 4 + wv] = q0;
        scratch[((1 * 4 + g) * 2 + 0) * 4 + wv] = s1;
        scratch[((1 * 4 + g) * 2 + 1) * 4 + wv] = q1;
    }
    __syncthreads();
    if (threadIdx.x < 16) {
        int gg = threadIdx.x >> 1, which = threadIdx.x & 1;
        float sum = scratch[(gg * 2 + which) * 4 + 0] + scratch[(gg * 2 + which) * 4 + 1] +
                    scratch[(gg * 2 + which) * 4 + 2] + scratch[(gg * 2 + which) * 4 + 3];
        atomicAdd(&stats2[(b * 8 + gg) * 2 + which], sum);
    }
}

// ---------------- K4: finalize GN2 stats ------------------------------------------
__global__ void k4_fin2(const float* __restrict__ stats2, float* __restrict__ s2f) {
    int i = threadIdx.x;
    if (i < 32) {
        const float n = 4.f * WH;
        float s = stats2[2 * i], q = stats2[2 * i + 1];
        float m = s / n;
        float var = q / n - m * m;
        s2f[2 * i] = m;
        s2f[2 * i + 1] = rsqrtf(var + 1e-5f);
    }
}

// ---------------- K5: GN2 apply + ReLU, float4 (in-place on d_out) ----------------
__global__ __launch_bounds__(256) void k5_gn(float4* __restrict__ out,
                                             const float* __restrict__ s2f,
                                             const float* __restrict__ gs,
                                             const float* __restrict__ gb) {
    int idx = blockIdx.x * 256 + threadIdx.x;
    int bo = idx >> 14;
    int b = bo >> 5;
    int o = bo & 31;
    int g = o >> 2;
    float mean = s2f[(b * 8 + g) * 2 + 0];
    float istd = s2f[(b * 8 + g) * 2 + 1];
    float sc = gs[o] * istd;
    float bi = gb[o] - mean * sc;
    float4 v = out[idx];
    v.x = fmaxf(fmaf(v.x, sc, bi), 0.f);
    v.y = fmaxf(fmaf(v.y, sc, bi), 0.f);
    v.z = fmaxf(fmaf(v.z, sc, bi), 0.f);
    v.w = fmaxf(fmaf(v.w, sc, bi), 0.f);
    out[idx] = v;
}

extern "C" void kernel_launch(void* const* d_in, const int* in_sizes, int n_in,
                              void* d_out, int out_size, void* d_ws, size_t ws_size,
                              hipStream_t stream) {
    const float* x        = (const float*)d_in[0];
    const float* w_off    = (const float*)d_in[1];
    const float* b_off    = (const float*)d_in[2];
    const float* go_scale = (const float*)d_in[3];
    const float* go_bias  = (const float*)d_in[4];
    const float* w_dsc    = (const float*)d_in[5];
    const float* b_dsc    = (const float*)d_in[6];
    const float* gn_scale = (const float*)d_in[7];
    const float* gn_bias  = (const float*)d_in[8];
    float* out = (float*)d_out;

    float* ws = (float*)d_ws;
    float* off_buf = ws;                                    // 2,621,440 f
    unsigned short* B3f  = (unsigned short*)(ws + 2621440); // 8192 us (4096 f)
    unsigned short* B8f  = (unsigned short*)(ws + 2625536); // 1024 us (512 f)
    unsigned short* B1f  = (unsigned short*)(ws + 2626048); // 4096 us (2048 f)
    unsigned short* B18f = (unsigned short*)(ws + 2628096); // 512 us (256 f)
    float* stats1 = ws + 2628352;                           // 40
    float* s1f    = stats1 + 40;                            // 40
    float* stats2 = s1f + 40;                               // 64
    float* s2f    = stats2 + 64;                            // 64

    k0_init<<<54, 256, 0, stream>>>(w_dsc, w_off, B3f, B8f, B1f, B18f, stats1, stats2);
    k1_conv<<<dim3(2, 128, BB), 256, 0, stream>>>(x, B1f, B18f, b_off, off_buf, stats1);
    k2_fin1<<<1, 64, 0, stream>>>(stats1, s1f);
    k3_sample<<<dim3(4, 64, BB), 256, 0, stream>>>(x, off_buf, s1f, go_scale, go_bias,
                                                   B3f, B8f, b_dsc, out, stats2);
    k4_fin2<<<1, 64, 0, stream>>>(stats2, s2f);
    k5_gn<<<8192, 256, 0, stream>>>((float4*)out, s2f, gn_scale, gn_bias);
}